// Round 20
// baseline (643.429 us; speedup 1.0000x reference)
//
#include <hip/hip_runtime.h>

#define ALPHA 0.9f
#define BETA  0.8f
#define K     25
#define B     128
#define T     16
#define IN_DIM 14400
#define NSL   8      // batch slices (= XCDs)
#define SW    16     // batch elems per slice
#define CF    96     // features per transpose tile
#define NCH   150    // IN_DIM / CF
// bf16 paired-t row: [feature][2][16] bf16 = 64B; serves TWO timesteps.
// Gather: 4 lanes/neuron (parity x octet), uint4 16B/lane -> one wave-load
// covers 16 complete rows serving 2 timesteps = half of r18's instruction
// count. uint4 (not ushort8 ext-vector: that type produced a reproducible
// 99MB-WRITE/124us scratch pathology in r16 AND r19; float4/uint4-class
// 16B loads have been clean in every round).

using u16 = unsigned short;

static __device__ __forceinline__ u16 f2bf(float f) {
  union { float f; unsigned u; } c; c.f = f;
  const unsigned r = c.u + 0x7FFFu + ((c.u >> 16) & 1u);  // RTNE
  return (u16)(r >> 16);
}
static __device__ __forceinline__ float bf_lo(unsigned u) {
  union { unsigned u; float f; } c; c.u = u << 16;        // low bf16
  return c.f;
}
static __device__ __forceinline__ float bf_hi(unsigned u) {
  union { unsigned u; float f; } c; c.u = u & 0xFFFF0000u; // high bf16
  return c.f;
}

// ---------------------------------------------------------------------------
// Slice-pinned pair-complete transpose (r13, proven clean). x slab [t0,t0+8)
// fp32 -> bf16 xTh[4tp][8e][IN][2][16]; every 64B row written complete by
// the owning XCD. Grid 1024 = residency at LB(256,4).
// ---------------------------------------------------------------------------
__global__ __launch_bounds__(256, 4) void transpose_pair_pinned(
    const float* __restrict__ x, u16* __restrict__ xTh, int t0, int slots) {
  __shared__ float lds[CF][33];
  const int e    = blockIdx.x & 7;
  const int slot = blockIdx.x >> 3;
  const int tid  = threadIdx.x;
  const int rid  = tid >> 3;        // 0..31
  const int fq   = tid & 7;
  const int tpar = rid >> 4;        // t parity
  const int bl   = rid & 15;
  const int b    = e * 16 + bl;

  const int ntiles = 4 * NCH;
  for (int ti = slot; ti < ntiles; ti += slots) {
    const int tp = ti / NCH;
    const int ch = ti - tp * NCH;
    const int i0 = ch * CF;
    const int t  = t0 + tp * 2 + tpar;
    const float* xr = x + ((size_t)b * T + t) * IN_DIM + i0;
#pragma unroll
    for (int pf = 0; pf < CF / 32; ++pf) {
      const float4 v = *(const float4*)&xr[pf * 32 + fq * 4];
      lds[pf * 32 + fq * 4 + 0][rid] = v.x;
      lds[pf * 32 + fq * 4 + 1][rid] = v.y;
      lds[pf * 32 + fq * 4 + 2][rid] = v.z;
      lds[pf * 32 + fq * 4 + 3][rid] = v.w;
    }
    __syncthreads();
#pragma unroll
    for (int wp = 0; wp < CF / 32; ++wp) {
      const int f = wp * 32 + rid;
      ushort4 ov;
      ov.x = f2bf(lds[f][fq * 4 + 0]);
      ov.y = f2bf(lds[f][fq * 4 + 1]);
      ov.z = f2bf(lds[f][fq * 4 + 2]);
      ov.w = f2bf(lds[f][fq * 4 + 3]);
      *(ushort4*)&xTh[(((size_t)tp * NSL + e) * IN_DIM + (i0 + f)) * 32 +
                      fq * 4] = ov;
    }
    __syncthreads();
  }
}

// ---------------------------------------------------------------------------
// Fused LCN+LIF, bf16 t-paired rows, uint4 16B gathers (8 bf16 = 8 batch
// elems of one parity per lane). 128 thr = 32 neurons x 4 lanes (parity x
// octet). idx/w in registers (r12-proven addressing); 5+5 double-buffered
// uint4 window (40 data regs). LIF parity pair via __shfl_xor(2); state
// fp32 in registers. LB(128,4) -> VGPR cap 128, 8 blk/CU -> residency
// 2048 >= all grids (L0 1800) so blockIdx%8 = XCD launch-exact.
// ---------------------------------------------------------------------------
template <int NTP>
__global__ __launch_bounds__(128, 4) void lcn_u4(
    const u16* __restrict__ hsrc, const float* __restrict__ w,
    const float* __restrict__ bias, const int* __restrict__ knn,
    u16* __restrict__ memout, float* __restrict__ state,
    int dim, int dprev, int load_state, int save_state) {
  const int e    = blockIdx.x & 7;        // slice -> XCD
  const int blk  = blockIdx.x >> 3;
  const int nl   = threadIdx.x >> 2;      // neuron in block (0..31)
  const int l4   = threadIdx.x & 3;
  const int half = l4 >> 1;               // t parity this lane handles
  const int oct  = l4 & 1;                // batch octet (8 elems)
  const int lofs = half * SW + oct * 8;   // u16 offset within paired row

  const int dd  = blk * 32 + nl;
  const bool act = dd < dim;
  const int d   = act ? dd : dim - 1;

  int   idx[K];
  float wr[K];
#pragma unroll
  for (int k = 0; k < K; ++k) {
    idx[k] = knn[d * K + k] * 32 + lofs;
    wr[k]  = w[d * K + k];
  }
  const float bi = bias[d];

  float4 sL = make_float4(0.f, 0.f, 0.f, 0.f), sH = sL, mL = sL, mH = sL;
  if (load_state) {
    const size_t so = ((size_t)e * dim + d) * SW + oct * 8;
    sL = *(const float4*)&state[so];
    sH = *(const float4*)&state[so + 4];
    mL = *(const float4*)&state[(size_t)NSL * dim * SW + so];
    mH = *(const float4*)&state[(size_t)NSL * dim * SW + so + 4];
  }

// accumulate 8 packed bf16 (uint4 v) * wk into aL (elems 0-3), aH (4-7)
#define FMA8U(wk, v)                          \
  do {                                        \
    aL.x = fmaf(wk, bf_lo((v).x), aL.x);      \
    aL.y = fmaf(wk, bf_hi((v).x), aL.y);      \
    aL.z = fmaf(wk, bf_lo((v).y), aL.z);      \
    aL.w = fmaf(wk, bf_hi((v).y), aL.w);      \
    aH.x = fmaf(wk, bf_lo((v).z), aH.x);      \
    aH.y = fmaf(wk, bf_hi((v).z), aH.y);      \
    aH.z = fmaf(wk, bf_lo((v).w), aH.z);      \
    aH.w = fmaf(wk, bf_hi((v).w), aH.w);      \
  } while (0)

  for (int tp = 0; tp < NTP; ++tp) {
    const u16* hp = hsrc + ((size_t)tp * NSL + e) * dprev * 32;
    uint4 ha[5], hb[5];
#pragma unroll
    for (int j = 0; j < 5; ++j) ha[j] = *(const uint4*)&hp[idx[j]];
#pragma unroll
    for (int j = 0; j < 5; ++j) hb[j] = *(const uint4*)&hp[idx[5 + j]];
    float4 aL = make_float4(bi, bi, bi, bi);
    float4 aH = make_float4(bi, bi, bi, bi);
#pragma unroll
    for (int j = 0; j < 5; ++j) FMA8U(wr[j], ha[j]);
#pragma unroll
    for (int j = 0; j < 5; ++j) ha[j] = *(const uint4*)&hp[idx[10 + j]];
#pragma unroll
    for (int j = 0; j < 5; ++j) FMA8U(wr[5 + j], hb[j]);
#pragma unroll
    for (int j = 0; j < 5; ++j) hb[j] = *(const uint4*)&hp[idx[15 + j]];
#pragma unroll
    for (int j = 0; j < 5; ++j) FMA8U(wr[10 + j], ha[j]);
#pragma unroll
    for (int j = 0; j < 5; ++j) ha[j] = *(const uint4*)&hp[idx[20 + j]];
#pragma unroll
    for (int j = 0; j < 5; ++j) FMA8U(wr[15 + j], hb[j]);
#pragma unroll
    for (int j = 0; j < 5; ++j) FMA8U(wr[20 + j], ha[j]);

    // exchange parities within the (neuron, octet) pair: lane ^ 2
    float4 oL, oH;
    oL.x = __shfl_xor(aL.x, 2, 64);
    oL.y = __shfl_xor(aL.y, 2, 64);
    oL.z = __shfl_xor(aL.z, 2, 64);
    oL.w = __shfl_xor(aL.w, 2, 64);
    oH.x = __shfl_xor(aH.x, 2, 64);
    oH.y = __shfl_xor(aH.y, 2, 64);
    oH.z = __shfl_xor(aH.z, 2, 64);
    oH.w = __shfl_xor(aH.w, 2, 64);
    const float4 p0L = half ? oL : aL;  // t even
    const float4 p0H = half ? oH : aH;
    const float4 p1L = half ? aL : oL;  // t odd
    const float4 p1H = half ? aH : oH;

    // LIF t-even (reset from PREVIOUS membrane)
    sL.x = ALPHA * sL.x + p0L.x;  sL.y = ALPHA * sL.y + p0L.y;
    sL.z = ALPHA * sL.z + p0L.z;  sL.w = ALPHA * sL.w + p0L.w;
    sH.x = ALPHA * sH.x + p0H.x;  sH.y = ALPHA * sH.y + p0H.y;
    sH.z = ALPHA * sH.z + p0H.z;  sH.w = ALPHA * sH.w + p0H.w;
    float4 meL, meH;
    meL.x = BETA * mL.x + sL.x - ((mL.x > 1.0f) ? 1.0f : 0.0f);
    meL.y = BETA * mL.y + sL.y - ((mL.y > 1.0f) ? 1.0f : 0.0f);
    meL.z = BETA * mL.z + sL.z - ((mL.z > 1.0f) ? 1.0f : 0.0f);
    meL.w = BETA * mL.w + sL.w - ((mL.w > 1.0f) ? 1.0f : 0.0f);
    meH.x = BETA * mH.x + sH.x - ((mH.x > 1.0f) ? 1.0f : 0.0f);
    meH.y = BETA * mH.y + sH.y - ((mH.y > 1.0f) ? 1.0f : 0.0f);
    meH.z = BETA * mH.z + sH.z - ((mH.z > 1.0f) ? 1.0f : 0.0f);
    meH.w = BETA * mH.w + sH.w - ((mH.w > 1.0f) ? 1.0f : 0.0f);
    // LIF t-odd
    sL.x = ALPHA * sL.x + p1L.x;  sL.y = ALPHA * sL.y + p1L.y;
    sL.z = ALPHA * sL.z + p1L.z;  sL.w = ALPHA * sL.w + p1L.w;
    sH.x = ALPHA * sH.x + p1H.x;  sH.y = ALPHA * sH.y + p1H.y;
    sH.z = ALPHA * sH.z + p1H.z;  sH.w = ALPHA * sH.w + p1H.w;
    mL.x = BETA * meL.x + sL.x - ((meL.x > 1.0f) ? 1.0f : 0.0f);
    mL.y = BETA * meL.y + sL.y - ((meL.y > 1.0f) ? 1.0f : 0.0f);
    mL.z = BETA * meL.z + sL.z - ((meL.z > 1.0f) ? 1.0f : 0.0f);
    mL.w = BETA * meL.w + sL.w - ((meL.w > 1.0f) ? 1.0f : 0.0f);
    mH.x = BETA * meH.x + sH.x - ((meH.x > 1.0f) ? 1.0f : 0.0f);
    mH.y = BETA * meH.y + sH.y - ((meH.y > 1.0f) ? 1.0f : 0.0f);
    mH.z = BETA * meH.z + sH.z - ((meH.z > 1.0f) ? 1.0f : 0.0f);
    mH.w = BETA * meH.w + sH.w - ((meH.w > 1.0f) ? 1.0f : 0.0f);

    if (act) {
      const float4 wvL = half ? mL : meL;  // this lane's parity
      const float4 wvH = half ? mH : meH;
      uint4 ov;
      ov.x = (unsigned)f2bf(wvL.x) | ((unsigned)f2bf(wvL.y) << 16);
      ov.y = (unsigned)f2bf(wvL.z) | ((unsigned)f2bf(wvL.w) << 16);
      ov.z = (unsigned)f2bf(wvH.x) | ((unsigned)f2bf(wvH.y) << 16);
      ov.w = (unsigned)f2bf(wvH.z) | ((unsigned)f2bf(wvH.w) << 16);
      *(uint4*)&memout[(((size_t)tp * NSL + e) * dim + d) * 32 + lofs] = ov;
    }
  }
#undef FMA8U

  if (save_state && act && half == 0) {
    const size_t so = ((size_t)e * dim + d) * SW + oct * 8;
    *(float4*)&state[so] = sL;
    *(float4*)&state[so + 4] = sH;
    *(float4*)&state[(size_t)NSL * dim * SW + so] = mL;
    *(float4*)&state[(size_t)NSL * dim * SW + so + 4] = mH;
  }
}

// Final FC on t=15 (pair 7, odd half) of mem4: [8tp][8e][450][2][16] bf16.
__global__ __launch_bounds__(128) void fc_kernel(
    const u16* __restrict__ mem4, const float* __restrict__ fc_w,
    const float* __restrict__ fc_b, float* __restrict__ out) {
  const int b  = threadIdx.x;
  const int e  = b >> 4;
  const int bl = b & 15;
  float a0 = fc_b[0], a1 = fc_b[1];
  const u16* base = mem4 + ((size_t)7 * NSL + e) * 450 * 32;
  for (int d = 0; d < 450; ++d) {
    union { unsigned u; float f; } c;
    c.u = ((unsigned)base[(size_t)d * 32 + SW + bl]) << 16;
    a0 += fc_w[d] * c.f;
    a1 += fc_w[450 + d] * c.f;
  }
  out[b * 2 + 0] = a0;
  out[b * 2 + 1] = a1;
}

extern "C" void kernel_launch(void* const* d_in, const int* in_sizes, int n_in,
                              void* d_out, int out_size, void* d_ws,
                              size_t ws_size, hipStream_t stream) {
  (void)in_sizes; (void)n_in; (void)out_size; (void)ws_size;
  const float* x = (const float*)d_in[0];
  const float* w[5];
  const float* bias[5];
  const int* knn[5];
  for (int i = 0; i < 5; ++i) {
    w[i]    = (const float*)d_in[1 + 3 * i];
    bias[i] = (const float*)d_in[2 + 3 * i];
    knn[i]  = (const int*)d_in[3 + 3 * i];
  }
  const float* fc_w = (const float*)d_in[16];
  const float* fc_b = (const float*)d_in[17];
  float* out = (float*)d_out;

  // Workspace: bf16 traces (paired layout [tp][8][d][2][16]) + fp32 state.
  //   A  : 14,745,600 u16  (mem0 [8tp][8][7200][32]; later mem2, mem4)
  //   XB : 14,745,600 u16  (xT half-slab [4tp]; later mem1 + mem3)
  //   S  : 2*8*7200*16 fp32 (layer-0 syn/mem carry between stages)
  u16* A  = (u16*)d_ws;
  u16* XB = A + 14745600;
  float* S = (float*)(XB + 14745600);

  u16* mem0 = A;
  u16* mem1 = XB;
  u16* mem2 = A;
  u16* mem3 = XB + 7372800;
  u16* mem4 = A;

  // ---- Layer 0 in two 8-t (4-pair) stages (xT half-slab reuse) ----
  for (int stage = 0; stage < 2; ++stage) {
    const int t0 = stage * 8;
    transpose_pair_pinned<<<128 * NSL, 256, 0, stream>>>(x, XB, t0, 128);
    lcn_u4<4><<<225 * NSL, 128, 0, stream>>>(
        XB, w[0], bias[0], knn[0], mem0 + (size_t)stage * 7372800, S,
        7200, IN_DIM, /*load=*/stage, /*save=*/stage == 0);
  }

  // ---- Layers 1..4, 8 pairs each, single dispatch ----
  lcn_u4<8><<<113 * NSL, 128, 0, stream>>>(mem0, w[1], bias[1], knn[1],
                                           mem1, nullptr, 3600, 7200, 0, 0);
  lcn_u4<8><<<57 * NSL, 128, 0, stream>>>(mem1, w[2], bias[2], knn[2],
                                          mem2, nullptr, 1800, 3600, 0, 0);
  lcn_u4<8><<<29 * NSL, 128, 0, stream>>>(mem2, w[3], bias[3], knn[3],
                                          mem3, nullptr, 900, 1800, 0, 0);
  lcn_u4<8><<<15 * NSL, 128, 0, stream>>>(mem3, w[4], bias[4], knn[4],
                                          mem4, nullptr, 450, 900, 0, 0);

  fc_kernel<<<1, 128, 0, stream>>>(mem4, fc_w, fc_b, out);
}

// Round 21
// 326.762 us; speedup vs baseline: 1.9691x; 1.9691x over previous
//
#include <hip/hip_runtime.h>

#define ALPHA 0.9f
#define BETA  0.8f
#define K     25
#define B     128
#define T     16
#define IN_DIM 14400
#define NSL   8      // batch slices (= XCDs)
#define SW    16     // batch elems per slice
#define NPG   32     // neurons per group in L0 (128 thr = 32 n x 4 quads)

using u16 = unsigned short;

static __device__ __forceinline__ u16 f2bf(float f) {
  union { float f; unsigned u; } c; c.f = f;
  const unsigned r = c.u + 0x7FFFu + ((c.u >> 16) & 1u);  // RTNE
  return (u16)(r >> 16);
}
static __device__ __forceinline__ float bf2f(u16 h) {
  union { unsigned u; float f; } c; c.u = ((unsigned)h) << 16;
  return c.f;
}

// ---------------------------------------------------------------------------
// fp32 transpose (rounds 6-10, proven): x (B,T,IN) slab [t0,t0+8) ->
// xTf[8tl][8e][IN][16] slice-major fp32.
// ---------------------------------------------------------------------------
__global__ __launch_bounds__(256) void transpose_x4_kernel(
    const float* __restrict__ x, float* __restrict__ xTf, int t0) {
  __shared__ float tile[64][65];
  const int tl = blockIdx.z;            // local t 0..7
  const int t  = t0 + tl;
  const int i0 = blockIdx.x * 64;       // feature tile
  const int b0 = blockIdx.y * 64;       // batch tile
  const int tid = threadIdx.x;

  const int fi = (tid & 15) * 4;        // feature quad
  const int bi = tid >> 4;              // batch row 0..15
#pragma unroll
  for (int p = 0; p < 4; ++p) {
    const int b = bi + p * 16;
    const float4 v = *(const float4*)&x[(size_t)(b0 + b) * (T * IN_DIM) +
                                        (size_t)t * IN_DIM + i0 + fi];
    tile[fi + 0][b] = v.x;
    tile[fi + 1][b] = v.y;
    tile[fi + 2][b] = v.z;
    tile[fi + 3][b] = v.w;
  }
  __syncthreads();
  const int bq = (tid & 15) * 4;        // batch quad (0,4,..,60)
  const int fr = tid >> 4;              // feature row 0..15
  const int e  = (b0 + bq) >> 4;        // slice
  const int bl = bq & 15;               // 0,4,8,12
#pragma unroll
  for (int p = 0; p < 4; ++p) {
    const int f = fr + p * 16;
    float4 v;
    v.x = tile[f][bq + 0];
    v.y = tile[f][bq + 1];
    v.z = tile[f][bq + 2];
    v.w = tile[f][bq + 3];
    *(float4*)&xTf[(((size_t)tl * NSL + e) * IN_DIM + (i0 + f)) * SW + bl] = v;
  }
}

// ---------------------------------------------------------------------------
// Layer 0: fp32 gather path (proven 68 us/stage, FETCH 31.7 MB), output
// converted to bf16 t-paired mem0 [tp][8e][7200][2][16]. Both parities of a
// row written by the SAME block on consecutive t iterations -> no cross-XCD
// partial-line RMW. 128 thr = 32 neurons x 4 quads; grid 225*8=1800 <= 2048
// residency at LB(128,4) -> blockIdx%8 = XCD exact. idx/w in registers.
// ---------------------------------------------------------------------------
__global__ __launch_bounds__(128, 4) void lcn0_f32(
    const float* __restrict__ hsrc, const float* __restrict__ w,
    const float* __restrict__ bias, const int* __restrict__ knn,
    u16* __restrict__ memout, float* __restrict__ state,
    int t0, int load_state, int save_state) {
  const int e  = blockIdx.x & 7;          // slice -> XCD
  const int g  = blockIdx.x >> 3;         // neuron group
  const int nl = threadIdx.x >> 2;        // neuron in group (0..31)
  const int bq = (threadIdx.x & 3) * 4;   // batch quad within slice
  const int d  = g * NPG + nl;            // 7200 = 225*32 exact

  int   idx[K];
  float wr[K];
#pragma unroll
  for (int k = 0; k < K; ++k) {
    idx[k] = knn[d * K + k] * SW + bq;
    wr[k]  = w[d * K + k];
  }
  const float bi = bias[d];

  float4 sy = make_float4(0.f, 0.f, 0.f, 0.f);
  float4 me = make_float4(0.f, 0.f, 0.f, 0.f);
  if (load_state) {
    const size_t so = ((size_t)e * 7200 + d) * SW + bq;
    sy = *(const float4*)&state[so];
    me = *(const float4*)&state[(size_t)NSL * 7200 * SW + so];
  }

  for (int tl = 0; tl < 8; ++tl) {
    const float* hp = hsrc + ((size_t)tl * NSL + e) * IN_DIM * SW;
    float4 ha[9], hb[8];
#pragma unroll
    for (int j = 0; j < 8; ++j) ha[j] = *(const float4*)&hp[idx[j]];
#pragma unroll
    for (int j = 0; j < 8; ++j) hb[j] = *(const float4*)&hp[idx[8 + j]];
    float4 a0 = make_float4(bi, bi, bi, bi);
    float4 a1 = make_float4(0.f, 0.f, 0.f, 0.f);
#pragma unroll
    for (int j = 0; j < 8; ++j) {
      const float wk = wr[j];
      if (j & 1) {
        a1.x = fmaf(wk, ha[j].x, a1.x);
        a1.y = fmaf(wk, ha[j].y, a1.y);
        a1.z = fmaf(wk, ha[j].z, a1.z);
        a1.w = fmaf(wk, ha[j].w, a1.w);
      } else {
        a0.x = fmaf(wk, ha[j].x, a0.x);
        a0.y = fmaf(wk, ha[j].y, a0.y);
        a0.z = fmaf(wk, ha[j].z, a0.z);
        a0.w = fmaf(wk, ha[j].w, a0.w);
      }
    }
#pragma unroll
    for (int j = 0; j < 9; ++j) ha[j] = *(const float4*)&hp[idx[16 + j]];
#pragma unroll
    for (int j = 0; j < 8; ++j) {
      const float wk = wr[8 + j];
      if (j & 1) {
        a1.x = fmaf(wk, hb[j].x, a1.x);
        a1.y = fmaf(wk, hb[j].y, a1.y);
        a1.z = fmaf(wk, hb[j].z, a1.z);
        a1.w = fmaf(wk, hb[j].w, a1.w);
      } else {
        a0.x = fmaf(wk, hb[j].x, a0.x);
        a0.y = fmaf(wk, hb[j].y, a0.y);
        a0.z = fmaf(wk, hb[j].z, a0.z);
        a0.w = fmaf(wk, hb[j].w, a0.w);
      }
    }
#pragma unroll
    for (int j = 0; j < 9; ++j) {
      const float wk = wr[16 + j];
      if (j & 1) {
        a1.x = fmaf(wk, ha[j].x, a1.x);
        a1.y = fmaf(wk, ha[j].y, a1.y);
        a1.z = fmaf(wk, ha[j].z, a1.z);
        a1.w = fmaf(wk, ha[j].w, a1.w);
      } else {
        a0.x = fmaf(wk, ha[j].x, a0.x);
        a0.y = fmaf(wk, ha[j].y, a0.y);
        a0.z = fmaf(wk, ha[j].z, a0.z);
        a0.w = fmaf(wk, ha[j].w, a0.w);
      }
    }
    const float4 acc = make_float4(a0.x + a1.x, a0.y + a1.y, a0.z + a1.z,
                                   a0.w + a1.w);
    sy.x = ALPHA * sy.x + acc.x;
    sy.y = ALPHA * sy.y + acc.y;
    sy.z = ALPHA * sy.z + acc.z;
    sy.w = ALPHA * sy.w + acc.w;
    float4 r;
    r.x = (me.x > 1.0f) ? 1.0f : 0.0f;  // reset from PREVIOUS membrane
    r.y = (me.y > 1.0f) ? 1.0f : 0.0f;
    r.z = (me.z > 1.0f) ? 1.0f : 0.0f;
    r.w = (me.w > 1.0f) ? 1.0f : 0.0f;
    me.x = BETA * me.x + sy.x - r.x;
    me.y = BETA * me.y + sy.y - r.y;
    me.z = BETA * me.z + sy.z - r.z;
    me.w = BETA * me.w + sy.w - r.w;
    // bf16 t-paired store: global t, pair index, parity slot
    const int t   = t0 + tl;
    const int tp  = t >> 1;
    const int par = t & 1;
    ushort4 ov;
    ov.x = f2bf(me.x);
    ov.y = f2bf(me.y);
    ov.z = f2bf(me.z);
    ov.w = f2bf(me.w);
    *(ushort4*)&memout[(((size_t)tp * NSL + e) * 7200 + d) * 32 + par * SW +
                       bq] = ov;
  }

  if (save_state) {
    const size_t so = ((size_t)e * 7200 + d) * SW + bq;
    *(float4*)&state[so] = sy;
    *(float4*)&state[(size_t)NSL * 7200 * SW + so] = me;
  }
}

// ---------------------------------------------------------------------------
// L1..L4: bf16 t-paired rows; 256 thr = 32 neurons x 8 lanes (parity x quad).
// ---------------------------------------------------------------------------
template <int NTP, int NPASS>
__global__ __launch_bounds__(256, 4) void lcn_pair_bf(
    const u16* __restrict__ hsrc, const float* __restrict__ w,
    const float* __restrict__ bias, const int* __restrict__ knn,
    u16* __restrict__ memout, float* __restrict__ state,
    int dim, int dprev, int nblk, int load_state, int save_state) {
  const int e    = blockIdx.x & 7;        // slice -> XCD
  const int blk  = blockIdx.x >> 3;
  const int nl   = threadIdx.x >> 3;      // neuron in block (0..31)
  const int l8   = threadIdx.x & 7;
  const int half = l8 >> 2;               // t parity handled by this lane
  const int bq   = (l8 & 3) * 4;          // batch quad

#pragma unroll 1
  for (int p = 0; p < NPASS; ++p) {
    const int dd = (blk + p * nblk) * 32 + nl;
    const bool act = dd < dim;
    const int d = act ? dd : dim - 1;

    int   idx[K];
    float wr[K];
#pragma unroll
    for (int k = 0; k < K; ++k) {
      idx[k] = knn[d * K + k] * 32 + half * SW + bq;
      wr[k]  = w[d * K + k];
    }
    const float bi = bias[d];

    float4 s = make_float4(0.f, 0.f, 0.f, 0.f);
    float4 m = make_float4(0.f, 0.f, 0.f, 0.f);
    if (load_state) {
      const size_t so = ((size_t)e * dim + d) * SW + bq;
      s = *(const float4*)&state[so];
      m = *(const float4*)&state[(size_t)NSL * dim * SW + so];
    }

    for (int tp = 0; tp < NTP; ++tp) {
      const u16* hp = hsrc + ((size_t)tp * NSL + e) * dprev * 32;
      ushort4 hv[13], hw[12];
#pragma unroll
      for (int j = 0; j < 13; ++j)
        hv[j] = *(const ushort4*)&hp[idx[j]];
#pragma unroll
      for (int j = 0; j < 12; ++j)
        hw[j] = *(const ushort4*)&hp[idx[13 + j]];
      float4 a0 = make_float4(bi, bi, bi, bi);
      float4 a1 = make_float4(0.f, 0.f, 0.f, 0.f);
#pragma unroll
      for (int j = 0; j < 13; ++j) {
        const float wk = wr[j];
        if (j & 1) {
          a1.x = fmaf(wk, bf2f(hv[j].x), a1.x);
          a1.y = fmaf(wk, bf2f(hv[j].y), a1.y);
          a1.z = fmaf(wk, bf2f(hv[j].z), a1.z);
          a1.w = fmaf(wk, bf2f(hv[j].w), a1.w);
        } else {
          a0.x = fmaf(wk, bf2f(hv[j].x), a0.x);
          a0.y = fmaf(wk, bf2f(hv[j].y), a0.y);
          a0.z = fmaf(wk, bf2f(hv[j].z), a0.z);
          a0.w = fmaf(wk, bf2f(hv[j].w), a0.w);
        }
      }
#pragma unroll
      for (int j = 0; j < 12; ++j) {
        const float wk = wr[13 + j];
        if (j & 1) {
          a1.x = fmaf(wk, bf2f(hw[j].x), a1.x);
          a1.y = fmaf(wk, bf2f(hw[j].y), a1.y);
          a1.z = fmaf(wk, bf2f(hw[j].z), a1.z);
          a1.w = fmaf(wk, bf2f(hw[j].w), a1.w);
        } else {
          a0.x = fmaf(wk, bf2f(hw[j].x), a0.x);
          a0.y = fmaf(wk, bf2f(hw[j].y), a0.y);
          a0.z = fmaf(wk, bf2f(hw[j].z), a0.z);
          a0.w = fmaf(wk, bf2f(hw[j].w), a0.w);
        }
      }
      float4 acc;
      acc.x = a0.x + a1.x;
      acc.y = a0.y + a1.y;
      acc.z = a0.z + a1.z;
      acc.w = a0.w + a1.w;
      float4 oth;
      oth.x = __shfl_xor(acc.x, 4, 64);
      oth.y = __shfl_xor(acc.y, 4, 64);
      oth.z = __shfl_xor(acc.z, 4, 64);
      oth.w = __shfl_xor(acc.w, 4, 64);
      const float4 pre0 = half ? oth : acc;  // t even
      const float4 pre1 = half ? acc : oth;  // t odd
      // LIF t-even (reset from PREVIOUS membrane)
      s.x = ALPHA * s.x + pre0.x;
      s.y = ALPHA * s.y + pre0.y;
      s.z = ALPHA * s.z + pre0.z;
      s.w = ALPHA * s.w + pre0.w;
      float4 meven;
      meven.x = BETA * m.x + s.x - ((m.x > 1.0f) ? 1.0f : 0.0f);
      meven.y = BETA * m.y + s.y - ((m.y > 1.0f) ? 1.0f : 0.0f);
      meven.z = BETA * m.z + s.z - ((m.z > 1.0f) ? 1.0f : 0.0f);
      meven.w = BETA * m.w + s.w - ((m.w > 1.0f) ? 1.0f : 0.0f);
      // LIF t-odd
      s.x = ALPHA * s.x + pre1.x;
      s.y = ALPHA * s.y + pre1.y;
      s.z = ALPHA * s.z + pre1.z;
      s.w = ALPHA * s.w + pre1.w;
      m.x = BETA * meven.x + s.x - ((meven.x > 1.0f) ? 1.0f : 0.0f);
      m.y = BETA * meven.y + s.y - ((meven.y > 1.0f) ? 1.0f : 0.0f);
      m.z = BETA * meven.z + s.z - ((meven.z > 1.0f) ? 1.0f : 0.0f);
      m.w = BETA * meven.w + s.w - ((meven.w > 1.0f) ? 1.0f : 0.0f);
      if (act) {
        const float4 wv = half ? m : meven;  // each lane stores its parity
        ushort4 ov;
        ov.x = f2bf(wv.x);
        ov.y = f2bf(wv.y);
        ov.z = f2bf(wv.z);
        ov.w = f2bf(wv.w);
        *(ushort4*)&memout[(((size_t)tp * NSL + e) * dim + d) * 32 +
                           half * SW + bq] = ov;
      }
    }

    if (save_state && act && half == 0) {
      const size_t so = ((size_t)e * dim + d) * SW + bq;
      *(float4*)&state[so] = s;
      *(float4*)&state[(size_t)NSL * dim * SW + so] = m;
    }
  }
}

// Final FC on t=15 (pair 7, odd half) of mem4: [8tp][8e][450][2][16] bf16.
__global__ __launch_bounds__(128) void fc_kernel(
    const u16* __restrict__ mem4, const float* __restrict__ fc_w,
    const float* __restrict__ fc_b, float* __restrict__ out) {
  const int b  = threadIdx.x;
  const int e  = b >> 4;
  const int bl = b & 15;
  float a0 = fc_b[0], a1 = fc_b[1];
  const u16* base = mem4 + ((size_t)7 * NSL + e) * 450 * 32;
  for (int d = 0; d < 450; ++d) {
    const float h = bf2f(base[(size_t)d * 32 + SW + bl]);
    a0 += fc_w[d] * h;
    a1 += fc_w[450 + d] * h;
  }
  out[b * 2 + 0] = a0;
  out[b * 2 + 1] = a1;
}

extern "C" void kernel_launch(void* const* d_in, const int* in_sizes, int n_in,
                              void* d_out, int out_size, void* d_ws,
                              size_t ws_size, hipStream_t stream) {
  (void)in_sizes; (void)n_in; (void)out_size; (void)ws_size;
  const float* x = (const float*)d_in[0];
  const float* w[5];
  const float* bias[5];
  const int* knn[5];
  for (int i = 0; i < 5; ++i) {
    w[i]    = (const float*)d_in[1 + 3 * i];
    bias[i] = (const float*)d_in[2 + 3 * i];
    knn[i]  = (const int*)d_in[3 + 3 * i];
  }
  const float* fc_w = (const float*)d_in[16];
  const float* fc_b = (const float*)d_in[17];
  float* out = (float*)d_out;

  // Workspace, 123.5 MB:
  //   xTf : 14,745,600 f   fp32 xT half-slab [8tl][8e][IN][16] (2 stages)
  //   S   :  1,843,200 f   L0 syn/mem carry
  //   mem0: 14,745,600 u16 [8tp][8e][7200][2][16]
  //   mem1:  7,372,800 u16 ... mem4: 921,600 u16
  float* xTf = (float*)d_ws;
  float* S   = xTf + 14745600;
  u16* mem0  = (u16*)(S + 1843200);
  u16* mem1  = mem0 + 14745600;
  u16* mem2  = mem1 + 7372800;
  u16* mem3  = mem2 + 3686400;
  u16* mem4  = mem3 + 1843200;

  // ---- Layer 0 in two 8-t stages: fp32 gather, bf16-paired output ----
  for (int stage = 0; stage < 2; ++stage) {
    const int t0 = stage * 8;
    transpose_x4_kernel<<<dim3(IN_DIM / 64, B / 64, 8), 256, 0, stream>>>(
        x, xTf, t0);
    lcn0_f32<<<225 * NSL, 128, 0, stream>>>(
        xTf, w[0], bias[0], knn[0], mem0, S, t0, /*load=*/stage,
        /*save=*/stage == 0);
  }

  // ---- Layers 1..4, bf16 t-paired ----
  lcn_pair_bf<8, 1><<<113 * NSL, 256, 0, stream>>>(
      mem0, w[1], bias[1], knn[1], mem1, nullptr, 3600, 7200, 113, 0, 0);
  lcn_pair_bf<8, 1><<<57 * NSL, 256, 0, stream>>>(
      mem1, w[2], bias[2], knn[2], mem2, nullptr, 1800, 3600, 57, 0, 0);
  lcn_pair_bf<8, 1><<<29 * NSL, 256, 0, stream>>>(
      mem2, w[3], bias[3], knn[3], mem3, nullptr, 900, 1800, 29, 0, 0);
  lcn_pair_bf<8, 1><<<15 * NSL, 256, 0, stream>>>(
      mem3, w[4], bias[4], knn[4], mem4, nullptr, 450, 900, 15, 0, 0);

  fc_kernel<<<1, 128, 0, stream>>>(mem4, fc_w, fc_b, out);
}